// Round 6
// baseline (248.414 us; speedup 1.0000x reference)
//
#include <hip/hip_runtime.h>
#include <hip/hip_bf16.h>

#define BB 128
#define LL 512
#define DD 300
#define HH 200
#define VV 50000
#define KP 320           // K padded (10 chunks of 32)
#define HP 208           // H padded (13 tiles of 16)
#define NEGBIG 1e12f

typedef __attribute__((ext_vector_type(8))) short bf16x8;
typedef __attribute__((ext_vector_type(4))) float f32x4;

__device__ __forceinline__ float bf2f(unsigned short u) {
  union { unsigned int i; float f; } v; v.i = ((unsigned int)u) << 16; return v.f;
}
__device__ __forceinline__ unsigned short f2bf(float f) {
  union { float f; unsigned int i; } v; v.f = f;
  unsigned int r = v.i + 0x7FFFu + ((v.i >> 16) & 1u);  // RNE (finite inputs)
  return (unsigned short)(r >> 16);
}

typedef const __attribute__((address_space(1))) unsigned int ga_u32;
typedef __attribute__((address_space(3))) unsigned int lds_u32;
__device__ __forceinline__ void gl_lds16(const void* g, void* l) {
  __builtin_amdgcn_global_load_lds((ga_u32*)g, (lds_u32*)l, 16, 0, 0);
}

// ---------------------------------------------------------------------------
// Kernel 1: fused gather + bf16 convert + emb_bf materialize + pool partials.
// Blocks 0..1023: (b, ch) tiles of 64 rows.
// Blocks 1024..1283: w1t prep (bf16 transpose [208][320], zero-padded).
// Blocks 1284..1987: mw1eff prep (layer-1 fold: mw1eff[k]=mw1[k]+mw1[300+k]
// for k<300 since x=[sattn,sattn,semb,oemb] duplicates sattn).
// ---------------------------------------------------------------------------
__global__ __launch_bounds__(256) void gather_pool(
    const int* __restrict__ words, const int* __restrict__ spos,
    const int* __restrict__ opos, const float* __restrict__ tab,
    const float* __restrict__ w1, const float* __restrict__ mw1,
    unsigned short* __restrict__ embbf, unsigned short* __restrict__ w1t,
    float* __restrict__ mw1eff,
    float* __restrict__ spart, float* __restrict__ opart) {
  int blk = blockIdx.x;
  int tid = threadIdx.x;

  if (blk >= 1284) {
    // ---- mw1eff prep: eff-K = 900 (sattn 0..299, semb 300..599, oemb 600..899)
    int idx = (blk - 1284) * 256 + tid;
    if (idx < 900 * HH) {
      int k = idx / HH, h = idx - k * HH;
      float v;
      if (k < 300) v = mw1[(size_t)k * HH + h] + mw1[(size_t)(300 + k) * HH + h];
      else v = mw1[(size_t)(k + 300) * HH + h];   // semb / oemb regions
      mw1eff[idx] = v;
    }
    return;
  }
  if (blk >= 1024) {
    // ---- w1t prep: [208][320] bf16, w1t[h][k] = w1[k*200+h] (prefs half)
    int idx = (blk - 1024) * 256 + tid;
    if (idx < HP * KP) {
      int h = idx / KP, k = idx - h * KP;
      float v = (h < HH && k < DD) ? w1[(size_t)k * HH + h] : 0.f;
      w1t[idx] = f2bf(v);
    }
    return;
  }

  int b = blk >> 3, ch = blk & 7, l0 = ch * 64;
  __shared__ int wd[64], sm[64], om[64];
  __shared__ unsigned short tile[64 * 328];   // row stride 328 (bank-friendly)
  if (tid < 64) {
    wd[tid] = words[b * LL + l0 + tid];
    sm[tid] = spos[b * LL + l0 + tid];
    om[tid] = opos[b * LL + l0 + tid];
  }
  __syncthreads();

  // gather + convert: 4 threads per row, 64B-coalesced float4 reads
  {
    int r = tid >> 2, qg = tid & 3;
    const float* srow = tab + (size_t)wd[r] * DD;
    unsigned short* trow = tile + r * 328;
#pragma unroll
    for (int i = 0; i < 19; ++i) {
      int q = qg + 4 * i;
      if (q < 75) {
        float4 v = *(const float4*)(srow + q * 4);
        ushort4 o;
        o.x = f2bf(v.x); o.y = f2bf(v.y); o.z = f2bf(v.z); o.w = f2bf(v.w);
        *(ushort4*)(trow + q * 4) = o;
      }
    }
    // zero-pad cols 300..327
    if (qg == 0) {
#pragma unroll
      for (int c = 300; c < 328; c += 4) {
        ushort4 z; z.x = z.y = z.z = z.w = 0;
        *(ushort4*)(trow + c) = z;
      }
    }
  }
  __syncthreads();

  // stream LDS tile -> emb_bf (linear [64][320] bf16 rows)
  {
    char* embdst = (char*)embbf + (size_t)(b * LL + l0) * 640;
#pragma unroll
    for (int j = 0; j < 10; ++j) {
      int g16 = j * 256 + tid;
      int row = g16 / 40, cb = g16 % 40;
      uint4 v = *(const uint4*)((const char*)tile + row * 656 + cb * 16);
      *(uint4*)(embdst + (size_t)g16 * 16) = v;
    }
  }

  // pool partials from LDS (keep where pos==0); unroll 8 for LDS-read ILP
  if (tid < 150) {
    float s0 = -NEGBIG, s1 = -NEGBIG, o0 = -NEGBIG, o1 = -NEGBIG;
#pragma unroll 8
    for (int r = 0; r < 64; ++r) {
      unsigned int v = *(const unsigned int*)((const char*)tile + r * 656 + tid * 4);
      float v0 = bf2f((unsigned short)(v & 0xffff));
      float v1 = bf2f((unsigned short)(v >> 16));
      if (sm[r] == 0) { s0 = fmaxf(s0, v0); s1 = fmaxf(s1, v1); }
      if (om[r] == 0) { o0 = fmaxf(o0, v0); o1 = fmaxf(o1, v1); }
    }
    size_t base = (size_t)(ch * BB + b) * DD + tid * 2;
    *(float2*)(spart + base) = make_float2(s0, s1);
    *(float2*)(opart + base) = make_float2(o0, o1);
  }
}

// ---------------------------------------------------------------------------
// Kernel 2: combine pool partials + fused preh. Grid B, block 320.
// preh[b,h] = b1[h] + sum_d semb[b,d] * w1[(300+d)*200+h]
// ---------------------------------------------------------------------------
__global__ __launch_bounds__(320) void combine_preh(
    const float* __restrict__ spart, const float* __restrict__ opart,
    const float* __restrict__ w1, const float* __restrict__ b1,
    float* __restrict__ semb, float* __restrict__ oemb,
    float* __restrict__ preh) {
  int b = blockIdx.x, t = threadIdx.x;
  __shared__ float se[DD];
  if (t < DD) {
    float s = -NEGBIG, o = -NEGBIG;
    for (int ch = 0; ch < 8; ++ch) {
      size_t base = (size_t)(ch * BB + b) * DD + t;
      s = fmaxf(s, spart[base]);
      o = fmaxf(o, opart[base]);
    }
    semb[(size_t)b * DD + t] = s;
    oemb[(size_t)b * DD + t] = o;
    se[t] = s;
  }
  __syncthreads();
  if (t < HH) {
    const float* w1b = w1 + (size_t)DD * HH + t;
    float acc = b1[t];
#pragma unroll 10
    for (int d = 0; d < DD; ++d) acc += se[d] * w1b[(size_t)d * HH];
    preh[(size_t)b * HH + t] = acc;
  }
}

// ---------------------------------------------------------------------------
// Kernel 3: scores via MFMA. Grid B*8 (64-pos tiles), block 256 (4 waves).
// A: 64x320 tile staged once via global_load_lds (swizzled, 40 KB) — ONE
//    barrier total.
// B: fragments loaded per k-chunk straight from global w1t (L2-resident,
//    160 KB shared by all 1024 blocks) into registers, 13-wide batches so
//    loads pipeline against MFMAs. No in-loop barriers; 3-4 blocks/CU.
// ---------------------------------------------------------------------------
__global__ __launch_bounds__(256) void scores_mfma(
    const unsigned short* __restrict__ embbf,
    const unsigned short* __restrict__ w1t, const float* __restrict__ preh,
    const float* __restrict__ w2, const float* __restrict__ b2,
    float* __restrict__ scores) {
  int tile = blockIdx.x;
  int b = tile >> 3, l0 = (tile & 7) * 64;
  int tid = threadIdx.x;
  int w = tid >> 6, lane = tid & 63;
  int lr = lane & 15, lq = lane >> 4;

  __shared__ unsigned short ldsA[64 * 320];   // 40960 B, swizzled

  const char* embbase = (const char*)embbf + (size_t)(b * LL + l0) * 640;
  int wbase16 = (w << 6);   // wave-uniform lane-0 16B-unit index offset

  // ---- stage A (10 instr/thread, fire-and-forget)
#pragma unroll
  for (int j = 0; j < 10; ++j) {
    int d16 = j * 256 + tid;
    int row = d16 / 40, c = d16 % 40;
    const void* src = embbase + row * 640 + (c ^ (row & 7)) * 16;
    void* dst = (char*)ldsA + (size_t)(j * 256 + wbase16) * 16;
    gl_lds16(src, dst);
  }
  __syncthreads();   // drains vmcnt(0) + barrier (the only barrier)

  f32x4 acc[13];
#pragma unroll
  for (int nt = 0; nt < 13; ++nt) acc[nt] = (f32x4){0.f, 0.f, 0.f, 0.f};

  const unsigned short* brow = w1t + (size_t)lr * KP + lq * 8;
  const char* aAddr = (const char*)ldsA + (w * 16 + lr) * 640;
  for (int kc = 0; kc < 10; ++kc) {
    bf16x8 a = *(const bf16x8*)(aAddr + (((kc * 4 + lq) ^ (lr & 7)) * 16));
    bf16x8 bv[13];
#pragma unroll
    for (int nt = 0; nt < 13; ++nt)
      bv[nt] = *(const bf16x8*)(brow + (size_t)nt * 16 * KP + kc * 32);
#pragma unroll
    for (int nt = 0; nt < 13; ++nt)
      acc[nt] = __builtin_amdgcn_mfma_f32_16x16x32_bf16(a, bv[nt], acc[nt], 0, 0, 0);
  }

  // ---- epilogue: score = b2 + sum_h w2[h]*tanh(acc + preh[b,h])
  float w2v[13], ph[13];
#pragma unroll
  for (int nt = 0; nt < 13; ++nt) {
    int h = nt * 16 + lr;
    bool v = (h < HH);
    w2v[nt] = v ? w2[h] : 0.f;
    ph[nt] = v ? preh[(size_t)b * HH + h] : 0.f;
  }
  float part[4] = {0.f, 0.f, 0.f, 0.f};
#pragma unroll
  for (int nt = 0; nt < 13; ++nt) {
#pragma unroll
    for (int r = 0; r < 4; ++r)
      part[r] += w2v[nt] * tanhf(acc[nt][r] + ph[nt]);
  }
#pragma unroll
  for (int off = 8; off; off >>= 1) {
#pragma unroll
    for (int r = 0; r < 4; ++r) part[r] += __shfl_xor(part[r], off, 16);
  }
  if (lr == 0) {
    float bb = b2[0];
#pragma unroll
    for (int r = 0; r < 4; ++r) {
      int pos = l0 + w * 16 + lq * 4 + r;
      scores[(size_t)b * LL + pos] = part[r] + bb;
    }
  }
}

// ---------------------------------------------------------------------------
// Kernel 4: fused softmax + PV partials. Grid B*8, block 256.
// Accumulate phase: 240 threads, 16B bf16x8 loads, 6-way row split (chain
// depth 64 -> 11), LDS partial-combine. Cols 300..319 of embbf are zeros.
// ---------------------------------------------------------------------------
__global__ __launch_bounds__(256) void pv_sm(
    const float* __restrict__ scores, const unsigned short* __restrict__ embbf,
    float* __restrict__ avpart) {
  int blk = blockIdx.x;
  int b = blk >> 3, ch = blk & 7, l0 = ch * 64;
  int tid = threadIdx.x;
  __shared__ float red[16];
  __shared__ float at[64];
  __shared__ float pacc[6][40][8];

  float s0 = scores[(size_t)b * LL + tid];
  float s1 = scores[(size_t)b * LL + 256 + tid];
  float m = fmaxf(s0, s1);
#pragma unroll
  for (int off = 32; off; off >>= 1) m = fmaxf(m, __shfl_xor(m, off, 64));
  if ((tid & 63) == 0) red[tid >> 6] = m;
  __syncthreads();
  float M = fmaxf(fmaxf(red[0], red[1]), fmaxf(red[2], red[3]));
  float e = expf(s0 - M) + expf(s1 - M);
#pragma unroll
  for (int off = 32; off; off >>= 1) e += __shfl_xor(e, off, 64);
  if ((tid & 63) == 0) red[8 + (tid >> 6)] = e;
  __syncthreads();
  float S = red[8] + red[9] + red[10] + red[11];
  if (tid < 64) at[tid] = expf(scores[(size_t)b * LL + l0 + tid] - M) / S;
  __syncthreads();

  int u = tid % 40, g = tid / 40;   // g in 0..5 for tid<240
  if (tid < 240) {
    float facc[8] = {0.f, 0.f, 0.f, 0.f, 0.f, 0.f, 0.f, 0.f};
    const char* base = (const char*)embbf + (size_t)(b * LL + l0) * 640 + u * 16;
#pragma unroll 4
    for (int r = g; r < 64; r += 6) {
      bf16x8 v = *(const bf16x8*)(base + (size_t)r * 640);
      float wgt = at[r];
#pragma unroll
      for (int q = 0; q < 8; ++q) facc[q] += wgt * bf2f((unsigned short)v[q]);
    }
#pragma unroll
    for (int q = 0; q < 8; ++q) pacc[g][u][q] = facc[q];
  }
  __syncthreads();
  if (tid < 160) {
    int u2 = tid >> 2, j = tid & 3;
    int d = u2 * 8 + j * 2;
    if (d < DD) {
      float v0 = 0.f, v1 = 0.f;
#pragma unroll
      for (int gg = 0; gg < 6; ++gg) {
        v0 += pacc[gg][u2][j * 2];
        v1 += pacc[gg][u2][j * 2 + 1];
      }
      *(float2*)(avpart + (size_t)(ch * BB + b) * DD + d) = make_float2(v0, v1);
    }
  }
}

// ---------------------------------------------------------------------------
// Kernel 5: MLP layer-1 partials over mw1eff (eff-K = 900).
// Grid 288 = (bc 0..15)*(kc 0..17), block 256. Each block: 8 b x 200 h x 50 k.
// ---------------------------------------------------------------------------
__global__ __launch_bounds__(256) void mlp1p(
    const float* __restrict__ avpart, const float* __restrict__ semb,
    const float* __restrict__ oemb, const float* __restrict__ mw1eff,
    float* __restrict__ p1) {
  int bc = blockIdx.x / 18, kc = blockIdx.x % 18;
  int tid = threadIdx.x;
  __shared__ float xT[50][8];
  for (int idx = tid; idx < 400; idx += 256) {
    int bb = idx & 7, kk = idx >> 3;
    int k = kc * 50 + kk;
    int b = bc * 8 + bb;
    int reg = k / 300, d = k - reg * 300;
    float v;
    if (reg == 0) {
      v = 0.f;
#pragma unroll
      for (int chh = 0; chh < 8; ++chh)
        v += avpart[(size_t)(chh * BB + b) * DD + d];
    } else if (reg == 1) {
      v = semb[(size_t)b * DD + d];
    } else {
      v = oemb[(size_t)b * DD + d];
    }
    xT[kk][bb] = v;
  }
  __syncthreads();
  if (tid >= HH) return;
  const float* wp = mw1eff + (size_t)(kc * 50) * HH + tid;
  float acc[8] = {0.f, 0.f, 0.f, 0.f, 0.f, 0.f, 0.f, 0.f};
#pragma unroll 5
  for (int kk = 0; kk < 50; ++kk) {
    float wv = wp[(size_t)kk * HH];
#pragma unroll
    for (int bb = 0; bb < 8; ++bb) acc[bb] += xT[kk][bb] * wv;
  }
#pragma unroll
  for (int bb = 0; bb < 8; ++bb)
    p1[((size_t)kc * BB + bc * 8 + bb) * HH + tid] = acc[bb];
}

// ---------------------------------------------------------------------------
// Kernel 6: MLP combine + relu + layer-2 + relu. Grid B (one b each), blk 256.
// ---------------------------------------------------------------------------
__global__ __launch_bounds__(256) void mlp2f(
    const float* __restrict__ p1, const float* __restrict__ mb1,
    const float* __restrict__ mw2, const float* __restrict__ mb2,
    float* __restrict__ out) {
  int b = blockIdx.x, tid = threadIdx.x;
  __shared__ float h1[HH];
  if (tid < HH) {
    float s = mb1[tid];
#pragma unroll
    for (int kc = 0; kc < 18; ++kc)
      s += p1[((size_t)kc * BB + b) * HH + tid];
    h1[tid] = fmaxf(s, 0.f);
  }
  __syncthreads();
  if (tid >= HH) return;
  const float* wp = mw2 + tid;
  float acc = mb2[tid];
#pragma unroll 8
  for (int k = 0; k < HH; ++k) acc += h1[k] * wp[(size_t)k * HH];
  out[(size_t)b * HH + tid] = fmaxf(acc, 0.f);
}

// ---------------------------------------------------------------------------
extern "C" void kernel_launch(void* const* d_in, const int* in_sizes, int n_in,
                              void* d_out, int out_size, void* d_ws, size_t ws_size,
                              hipStream_t stream) {
  const int* words = (const int*)d_in[0];
  const int* spos  = (const int*)d_in[1];
  const int* opos  = (const int*)d_in[2];
  const float* tab = (const float*)d_in[3];
  const float* w1  = (const float*)d_in[4];
  const float* b1  = (const float*)d_in[5];
  const float* w2  = (const float*)d_in[6];
  const float* b2  = (const float*)d_in[7];
  const float* mw1 = (const float*)d_in[8];
  const float* mb1 = (const float*)d_in[9];
  const float* mw2 = (const float*)d_in[10];
  const float* mb2 = (const float*)d_in[11];
  float* out = (float*)d_out;

  // workspace carving (bytes)
  char* p = (char*)d_ws;
  unsigned short* embbf = (unsigned short*)p; p += (size_t)BB * LL * KP * 2;  // 41.9 MB
  unsigned short* w1t   = (unsigned short*)p; p += (size_t)HP * KP * 2;       // 133 KB
  float* mw1eff = (float*)p; p += (size_t)900 * HH * 4;                       // 720 KB
  float* spart  = (float*)p; p += (size_t)8 * BB * DD * 4;
  float* opart  = (float*)p; p += (size_t)8 * BB * DD * 4;
  float* avpart = (float*)p; p += (size_t)8 * BB * DD * 4;
  float* semb   = (float*)p; p += (size_t)BB * DD * 4;
  float* oemb   = (float*)p; p += (size_t)BB * DD * 4;
  float* preh   = (float*)p; p += (size_t)BB * HH * 4;
  float* scores = (float*)p; p += (size_t)BB * LL * 4;
  float* p1     = (float*)p; p += (size_t)18 * BB * HH * 4;                   // 1.84 MB

  gather_pool<<<dim3(1988), dim3(256), 0, stream>>>(
      words, spos, opos, tab, w1, mw1, embbf, w1t, mw1eff, spart, opart);
  combine_preh<<<dim3(BB), dim3(320), 0, stream>>>(
      spart, opart, w1, b1, semb, oemb, preh);
  scores_mfma<<<dim3(BB * 8), dim3(256), 0, stream>>>(
      embbf, w1t, preh, w2, b2, scores);
  pv_sm<<<dim3(BB * 8), dim3(256), 0, stream>>>(scores, embbf, avpart);
  mlp1p<<<dim3(288), dim3(256), 0, stream>>>(avpart, semb, oemb, mw1eff, p1);
  mlp2f<<<dim3(BB), dim3(256), 0, stream>>>(p1, mb1, mw2, mb2, out);
}

// Round 8
// 206.343 us; speedup vs baseline: 1.2039x; 1.2039x over previous
//
#include <hip/hip_runtime.h>
#include <hip/hip_bf16.h>

#define BB 128
#define LL 512
#define DD 300
#define HH 200
#define VV 50000
#define KP 320           // K padded (10 chunks of 32)
#define NEGBIG 1e12f

typedef __attribute__((ext_vector_type(8))) short bf16x8;
typedef __attribute__((ext_vector_type(4))) float f32x4;

__device__ __forceinline__ float bf2f(unsigned short u) {
  union { unsigned int i; float f; } v; v.i = ((unsigned int)u) << 16; return v.f;
}
__device__ __forceinline__ unsigned short f2bf(float f) {
  union { float f; unsigned int i; } v; v.f = f;
  unsigned int r = v.i + 0x7FFFu + ((v.i >> 16) & 1u);  // RNE (finite inputs)
  return (unsigned short)(r >> 16);
}

typedef const __attribute__((address_space(1))) unsigned int ga_u32;
typedef __attribute__((address_space(3))) unsigned int lds_u32;
__device__ __forceinline__ void gl_lds16(const void* g, void* l) {
  __builtin_amdgcn_global_load_lds((ga_u32*)g, (lds_u32*)l, 16, 0, 0);
}

// ---------------------------------------------------------------------------
// Kernel 1: fused gather + bf16 convert + emb_bf materialize + pool partials.
// Blocks 0..2047: (b, ch) tiles of 32 rows (b=blk>>4, ch=blk&15).
// Blocks 2048..2087: w1s2 prep (pre-swizzled chunk-major B for scores_mfma).
// Blocks 2088..2791: mw1eff prep (layer-1 fold: mw1eff[k]=mw1[k]+mw1[300+k]
// for k<300 since x=[sattn,sattn,semb,oemb] duplicates sattn).
// ---------------------------------------------------------------------------
__global__ __launch_bounds__(256) void gather_pool(
    const int* __restrict__ words, const int* __restrict__ spos,
    const int* __restrict__ opos, const float* __restrict__ tab,
    const float* __restrict__ w1, const float* __restrict__ mw1,
    unsigned short* __restrict__ embbf, unsigned short* __restrict__ w1s2,
    float* __restrict__ mw1eff,
    float* __restrict__ spart, float* __restrict__ opart) {
  int blk = blockIdx.x;
  int tid = threadIdx.x;

  if (blk >= 2088) {
    // ---- mw1eff prep: eff-K = 900 (sattn 0..299, semb 300..599, oemb 600..899)
    int idx = (blk - 2088) * 256 + tid;
    if (idx < 900 * HH) {
      int k = idx / HH, h = idx - k * HH;
      float v;
      if (k < 300) v = mw1[(size_t)k * HH + h] + mw1[(size_t)(300 + k) * HH + h];
      else v = mw1[(size_t)(k + 300) * HH + h];   // semb / oemb regions
      mw1eff[idx] = v;
    }
    return;
  }
  if (blk >= 2048) {
    // ---- w1s2 prep: 40 blocks x 256 threads = 10240 c16 units
    int u = (blk - 2048) * 256 + tid;
    int kc = u >> 10;
    int rem = u & 1023;
    int row = rem >> 2, c16 = rem & 3;
    int s = (row ^ (row >> 2)) & 3;
    int kb = kc * 32 + ((c16 ^ s) << 3);
    bf16x8 o;
#pragma unroll
    for (int j = 0; j < 8; ++j) {
      int k = kb + j;
      float v = (k < DD && row < HH) ? w1[(size_t)k * HH + row] : 0.f;
      o[j] = (short)f2bf(v);
    }
    *(bf16x8*)(w1s2 + (size_t)u * 8) = o;
    return;
  }

  int b = blk >> 4, ch = blk & 15, l0 = ch * 32;
  __shared__ int wd[32], sm[32], om[32];
  __shared__ unsigned short tile[32 * 328];   // row stride 328 (bank-friendly)
  if (tid < 32) {
    wd[tid] = words[b * LL + l0 + tid];
    sm[tid] = spos[b * LL + l0 + tid];
    om[tid] = opos[b * LL + l0 + tid];
  }
  __syncthreads();

  // gather + convert: 8 threads per row, 64B-coalesced float4 reads
  {
    int r = tid >> 3, qg = tid & 7;
    const float* srow = tab + (size_t)wd[r] * DD;
    unsigned short* trow = tile + r * 328;
#pragma unroll
    for (int i = 0; i < 10; ++i) {
      int q = qg + 8 * i;
      if (q < 75) {
        float4 v = *(const float4*)(srow + q * 4);
        ushort4 o;
        o.x = f2bf(v.x); o.y = f2bf(v.y); o.z = f2bf(v.z); o.w = f2bf(v.w);
        *(ushort4*)(trow + q * 4) = o;
      }
    }
    // zero-pad cols 300..327
    if (qg == 0) {
#pragma unroll
      for (int c = 300; c < 328; c += 4) {
        ushort4 z; z.x = z.y = z.z = z.w = 0;
        *(ushort4*)(trow + c) = z;
      }
    }
  }
  __syncthreads();

  // stream LDS tile -> emb_bf (linear [32][320] bf16 rows): 1280 16B units
  {
    char* embdst = (char*)embbf + (size_t)(b * LL + l0) * 640;
#pragma unroll
    for (int j = 0; j < 5; ++j) {
      int g16 = j * 256 + tid;
      int row = g16 / 40, cb = g16 % 40;
      uint4 v = *(const uint4*)((const char*)tile + row * 656 + cb * 16);
      *(uint4*)(embdst + (size_t)g16 * 16) = v;
    }
  }

  // pool partials from LDS (keep where pos==0); unroll 8 for LDS-read ILP
  if (tid < 150) {
    float s0 = -NEGBIG, s1 = -NEGBIG, o0 = -NEGBIG, o1 = -NEGBIG;
#pragma unroll 8
    for (int r = 0; r < 32; ++r) {
      unsigned int v = *(const unsigned int*)((const char*)tile + r * 656 + tid * 4);
      float v0 = bf2f((unsigned short)(v & 0xffff));
      float v1 = bf2f((unsigned short)(v >> 16));
      if (sm[r] == 0) { s0 = fmaxf(s0, v0); s1 = fmaxf(s1, v1); }
      if (om[r] == 0) { o0 = fmaxf(o0, v0); o1 = fmaxf(o1, v1); }
    }
    size_t base = (size_t)(ch * BB + b) * DD + tid * 2;
    *(float2*)(spart + base) = make_float2(s0, s1);
    *(float2*)(opart + base) = make_float2(o0, o1);
  }
}

// ---------------------------------------------------------------------------
// Kernel 2: combine pool partials (16 chunks) + fused preh. Grid B, block 320.
// preh[b,h] = b1[h] + sum_d semb[b,d] * w1[(300+d)*200+h]
// ---------------------------------------------------------------------------
__global__ __launch_bounds__(320) void combine_preh(
    const float* __restrict__ spart, const float* __restrict__ opart,
    const float* __restrict__ w1, const float* __restrict__ b1,
    float* __restrict__ semb, float* __restrict__ oemb,
    float* __restrict__ preh) {
  int b = blockIdx.x, t = threadIdx.x;
  __shared__ float se[DD];
  if (t < DD) {
    float s = -NEGBIG, o = -NEGBIG;
    for (int ch = 0; ch < 16; ++ch) {
      size_t base = (size_t)(ch * BB + b) * DD + t;
      s = fmaxf(s, spart[base]);
      o = fmaxf(o, opart[base]);
    }
    semb[(size_t)b * DD + t] = s;
    oemb[(size_t)b * DD + t] = o;
    se[t] = s;
  }
  __syncthreads();
  if (t < HH) {
    const float* w1b = w1 + (size_t)DD * HH + t;
    float acc = b1[t];
#pragma unroll 10
    for (int d = 0; d < DD; ++d) acc += se[d] * w1b[(size_t)d * HH];
    preh[(size_t)b * HH + t] = acc;
  }
}

// ---------------------------------------------------------------------------
// Kernel 3: scores via MFMA, LDS-staged (round-5 verified version).
// Grid B*8 (64-pos tiles), block 256.
// A: full 64x320 tile staged once via global_load_lds, col16 XOR (row&7) swz.
// B: w1s2 chunk (16KB, pre-swizzled, chunk-major) double-buffered, 2-phase.
// NOTE: MFMA operands stay LDS-fed — strided-global B regs regressed 2x
// (rounds 2 & 6: 85/77us vs ~31us for this structure).
// ---------------------------------------------------------------------------
__global__ __launch_bounds__(256) void scores_mfma(
    const unsigned short* __restrict__ embbf,
    const unsigned short* __restrict__ w1s2, const float* __restrict__ preh,
    const float* __restrict__ w2, const float* __restrict__ b2,
    float* __restrict__ scores) {
  int tile = blockIdx.x;
  int b = tile >> 3, l0 = (tile & 7) * 64;
  int tid = threadIdx.x;
  int w = tid >> 6, lane = tid & 63;
  int lr = lane & 15, lq = lane >> 4;

  __shared__ unsigned short ldsA[64 * 320];        // 40960 B, swizzled
  __shared__ unsigned short ldsB[2][256 * 32];     // 2 x 16384 B

  const char* embbase = (const char*)embbf + (size_t)(b * LL + l0) * 640;
  int wbase16 = (w << 6);   // wave-uniform lane-0 16B-unit index offset

  // ---- prologue: stage A (10 instr/thread) + B chunk 0 (4 instr/thread)
#pragma unroll
  for (int j = 0; j < 10; ++j) {
    int d16 = j * 256 + tid;
    int row = d16 / 40, c = d16 % 40;
    const void* src = embbase + row * 640 + (c ^ (row & 7)) * 16;
    void* dst = (char*)ldsA + (size_t)(j * 256 + wbase16) * 16;
    gl_lds16(src, dst);
  }
  {
    const char* srcb = (const char*)w1s2;  // kc = 0
#pragma unroll
    for (int j = 0; j < 4; ++j)
      gl_lds16(srcb + (size_t)(j * 256 + tid) * 16,
               (char*)&ldsB[0][0] + (size_t)(j * 256 + wbase16) * 16);
  }
  __syncthreads();   // drains vmcnt(0) + barrier

  f32x4 acc[13];
#pragma unroll
  for (int nt = 0; nt < 13; ++nt) acc[nt] = (f32x4){0.f, 0.f, 0.f, 0.f};

  int slr = (lr ^ (lr >> 2)) & 3;
  const char* aAddr = (const char*)ldsA + (w * 16 + lr) * 640;
  int cur = 0;
  for (int kc = 0; kc < 10; ++kc) {
    if (kc < 9) {   // stage next chunk into the other buffer
      const char* srcb = (const char*)w1s2 + (size_t)(kc + 1) * 16384;
#pragma unroll
      for (int j = 0; j < 4; ++j)
        gl_lds16(srcb + (size_t)(j * 256 + tid) * 16,
                 (char*)&ldsB[cur ^ 1][0] + (size_t)(j * 256 + wbase16) * 16);
    }
    bf16x8 a = *(const bf16x8*)(aAddr + (((kc * 4 + lq) ^ (lr & 7)) * 16));
    const char* bbase = (const char*)&ldsB[cur][0] + lr * 64 + ((lq ^ slr) * 16);
#pragma unroll
    for (int nt = 0; nt < 13; ++nt) {
      bf16x8 bv = *(const bf16x8*)(bbase + nt * 16 * 64);
      acc[nt] = __builtin_amdgcn_mfma_f32_16x16x32_bf16(a, bv, acc[nt], 0, 0, 0);
    }
    __syncthreads();   // vmcnt(0) + lgkmcnt(0) + barrier: next buffer ready
    cur ^= 1;
  }

  // ---- epilogue: score = b2 + sum_h w2[h]*tanh(acc + preh[b,h])
  float w2v[13], ph[13];
#pragma unroll
  for (int nt = 0; nt < 13; ++nt) {
    int h = nt * 16 + lr;
    bool v = (h < HH);
    w2v[nt] = v ? w2[h] : 0.f;
    ph[nt] = v ? preh[(size_t)b * HH + h] : 0.f;
  }
  float part[4] = {0.f, 0.f, 0.f, 0.f};
#pragma unroll
  for (int nt = 0; nt < 13; ++nt) {
#pragma unroll
    for (int r = 0; r < 4; ++r)
      part[r] += w2v[nt] * tanhf(acc[nt][r] + ph[nt]);
  }
#pragma unroll
  for (int off = 8; off; off >>= 1) {
#pragma unroll
    for (int r = 0; r < 4; ++r) part[r] += __shfl_xor(part[r], off, 16);
  }
  if (lr == 0) {
    float bb = b2[0];
#pragma unroll
    for (int r = 0; r < 4; ++r) {
      int pos = l0 + w * 16 + lq * 4 + r;
      scores[(size_t)b * LL + pos] = part[r] + bb;
    }
  }
}

// ---------------------------------------------------------------------------
// Kernel 4: fused softmax + PV partials. Grid B*8, block 256.
// Accumulate phase: 240 threads, 16B bf16x8 loads, 6-way row split (chain
// depth 64 -> 11), LDS partial-combine. Cols 300..319 of embbf are zeros.
// ---------------------------------------------------------------------------
__global__ __launch_bounds__(256) void pv_sm(
    const float* __restrict__ scores, const unsigned short* __restrict__ embbf,
    float* __restrict__ avpart) {
  int blk = blockIdx.x;
  int b = blk >> 3, ch = blk & 7, l0 = ch * 64;
  int tid = threadIdx.x;
  __shared__ float red[16];
  __shared__ float at[64];
  __shared__ float pacc[6][40][8];

  float s0 = scores[(size_t)b * LL + tid];
  float s1 = scores[(size_t)b * LL + 256 + tid];
  float m = fmaxf(s0, s1);
#pragma unroll
  for (int off = 32; off; off >>= 1) m = fmaxf(m, __shfl_xor(m, off, 64));
  if ((tid & 63) == 0) red[tid >> 6] = m;
  __syncthreads();
  float M = fmaxf(fmaxf(red[0], red[1]), fmaxf(red[2], red[3]));
  float e = expf(s0 - M) + expf(s1 - M);
#pragma unroll
  for (int off = 32; off; off >>= 1) e += __shfl_xor(e, off, 64);
  if ((tid & 63) == 0) red[8 + (tid >> 6)] = e;
  __syncthreads();
  float S = red[8] + red[9] + red[10] + red[11];
  if (tid < 64) at[tid] = expf(scores[(size_t)b * LL + l0 + tid] - M) / S;
  __syncthreads();

  int u = tid % 40, g = tid / 40;   // g in 0..5 for tid<240
  if (tid < 240) {
    float facc[8] = {0.f, 0.f, 0.f, 0.f, 0.f, 0.f, 0.f, 0.f};
    const char* base = (const char*)embbf + (size_t)(b * LL + l0) * 640 + u * 16;
#pragma unroll 4
    for (int r = g; r < 64; r += 6) {
      bf16x8 v = *(const bf16x8*)(base + (size_t)r * 640);
      float wgt = at[r];
#pragma unroll
      for (int q = 0; q < 8; ++q) facc[q] += wgt * bf2f((unsigned short)v[q]);
    }
#pragma unroll
    for (int q = 0; q < 8; ++q) pacc[g][u][q] = facc[q];
  }
  __syncthreads();
  if (tid < 160) {
    int u2 = tid >> 2, j = tid & 3;
    int d = u2 * 8 + j * 2;
    if (d < DD) {
      float v0 = 0.f, v1 = 0.f;
#pragma unroll
      for (int gg = 0; gg < 6; ++gg) {
        v0 += pacc[gg][u2][j * 2];
        v1 += pacc[gg][u2][j * 2 + 1];
      }
      *(float2*)(avpart + (size_t)(ch * BB + b) * DD + d) = make_float2(v0, v1);
    }
  }
}

// ---------------------------------------------------------------------------
// Kernel 5: MLP layer-1 partials over mw1eff (eff-K = 900).
// Grid 288 = (bc 0..15)*(kc 0..17), block 256. Each block: 8 b x 200 h x 50 k.
// ---------------------------------------------------------------------------
__global__ __launch_bounds__(256) void mlp1p(
    const float* __restrict__ avpart, const float* __restrict__ semb,
    const float* __restrict__ oemb, const float* __restrict__ mw1eff,
    float* __restrict__ p1) {
  int bc = blockIdx.x / 18, kc = blockIdx.x % 18;
  int tid = threadIdx.x;
  __shared__ float xT[50][8];
  for (int idx = tid; idx < 400; idx += 256) {
    int bb = idx & 7, kk = idx >> 3;
    int k = kc * 50 + kk;
    int b = bc * 8 + bb;
    int reg = k / 300, d = k - reg * 300;
    float v;
    if (reg == 0) {
      v = 0.f;
#pragma unroll
      for (int chh = 0; chh < 8; ++chh)
        v += avpart[(size_t)(chh * BB + b) * DD + d];
    } else if (reg == 1) {
      v = semb[(size_t)b * DD + d];
    } else {
      v = oemb[(size_t)b * DD + d];
    }
    xT[kk][bb] = v;
  }
  __syncthreads();
  if (tid >= HH) return;
  const float* wp = mw1eff + (size_t)(kc * 50) * HH + tid;
  float acc[8] = {0.f, 0.f, 0.f, 0.f, 0.f, 0.f, 0.f, 0.f};
#pragma unroll 5
  for (int kk = 0; kk < 50; ++kk) {
    float wv = wp[(size_t)kk * HH];
#pragma unroll
    for (int bb = 0; bb < 8; ++bb) acc[bb] += xT[kk][bb] * wv;
  }
#pragma unroll
  for (int bb = 0; bb < 8; ++bb)
    p1[((size_t)kc * BB + bc * 8 + bb) * HH + tid] = acc[bb];
}

// ---------------------------------------------------------------------------
// Kernel 6: MLP combine + relu + layer-2 + relu. Grid B (one b each), blk 256.
// ---------------------------------------------------------------------------
__global__ __launch_bounds__(256) void mlp2f(
    const float* __restrict__ p1, const float* __restrict__ mb1,
    const float* __restrict__ mw2, const float* __restrict__ mb2,
    float* __restrict__ out) {
  int b = blockIdx.x, tid = threadIdx.x;
  __shared__ float h1[HH];
  if (tid < HH) {
    float s = mb1[tid];
#pragma unroll
    for (int kc = 0; kc < 18; ++kc)
      s += p1[((size_t)kc * BB + b) * HH + tid];
    h1[tid] = fmaxf(s, 0.f);
  }
  __syncthreads();
  if (tid >= HH) return;
  const float* wp = mw2 + tid;
  float acc = mb2[tid];
#pragma unroll 8
  for (int k = 0; k < HH; ++k) acc += h1[k] * wp[(size_t)k * HH];
  out[(size_t)b * HH + tid] = fmaxf(acc, 0.f);
}

// ---------------------------------------------------------------------------
extern "C" void kernel_launch(void* const* d_in, const int* in_sizes, int n_in,
                              void* d_out, int out_size, void* d_ws, size_t ws_size,
                              hipStream_t stream) {
  const int* words = (const int*)d_in[0];
  const int* spos  = (const int*)d_in[1];
  const int* opos  = (const int*)d_in[2];
  const float* tab = (const float*)d_in[3];
  const float* w1  = (const float*)d_in[4];
  const float* b1  = (const float*)d_in[5];
  const float* w2  = (const float*)d_in[6];
  const float* b2  = (const float*)d_in[7];
  const float* mw1 = (const float*)d_in[8];
  const float* mb1 = (const float*)d_in[9];
  const float* mw2 = (const float*)d_in[10];
  const float* mb2 = (const float*)d_in[11];
  float* out = (float*)d_out;

  // workspace carving (bytes)
  char* p = (char*)d_ws;
  unsigned short* embbf = (unsigned short*)p; p += (size_t)BB * LL * KP * 2;  // 41.9 MB
  unsigned short* w1s2  = (unsigned short*)p; p += (size_t)10 * 256 * 4 * 16; // 160 KB
  float* mw1eff = (float*)p; p += (size_t)900 * HH * 4;                       // 720 KB
  float* spart  = (float*)p; p += (size_t)16 * BB * DD * 4;                   // 2.4 MB
  float* opart  = (float*)p; p += (size_t)16 * BB * DD * 4;
  float* avpart = (float*)p; p += (size_t)8 * BB * DD * 4;
  float* semb   = (float*)p; p += (size_t)BB * DD * 4;
  float* oemb   = (float*)p; p += (size_t)BB * DD * 4;
  float* preh   = (float*)p; p += (size_t)BB * HH * 4;
  float* scores = (float*)p; p += (size_t)BB * LL * 4;
  float* p1     = (float*)p; p += (size_t)18 * BB * HH * 4;                   // 1.84 MB

  gather_pool<<<dim3(2792), dim3(256), 0, stream>>>(
      words, spos, opos, tab, w1, mw1, embbf, w1s2, mw1eff, spart, opart);
  combine_preh<<<dim3(BB), dim3(320), 0, stream>>>(
      spart, opart, w1, b1, semb, oemb, preh);
  scores_mfma<<<dim3(BB * 8), dim3(256), 0, stream>>>(
      embbf, w1s2, preh, w2, b2, scores);
  pv_sm<<<dim3(BB * 8), dim3(256), 0, stream>>>(scores, embbf, avpart);
  mlp1p<<<dim3(288), dim3(256), 0, stream>>>(avpart, semb, oemb, mw1eff, p1);
  mlp2f<<<dim3(BB), dim3(256), 0, stream>>>(p1, mb1, mw2, mb2, out);
}